// Round 20
// baseline (316.861 us; speedup 1.0000x reference)
//
#include <hip/hip_runtime.h>
#include <hip/hip_bf16.h>

typedef __bf16 bf16;
typedef __attribute__((ext_vector_type(2))) __bf16 bf16x2;
typedef __attribute__((ext_vector_type(4))) __bf16 bf16x4;
typedef __attribute__((ext_vector_type(8))) __bf16 bf16x8;
typedef __attribute__((ext_vector_type(4))) float f32x4;

#define NB 2
#define SEQ 1024
#define HIDN 4096
#define NH 32
#define NKV 8
#define DH 128
#define QKV_N 6144
static constexpr float SCALE = 0.08838834764831845f;  // 1/sqrt(128)

#define MFMA(a, b, c) __builtin_amdgcn_mfma_f32_16x16x32_bf16((a), (b), (c), 0, 0, 0)

__device__ __forceinline__ void async16(const void* g, void* l) {
  __builtin_amdgcn_global_load_lds(
      (const __attribute__((address_space(1))) unsigned int*)g,
      (__attribute__((address_space(3))) unsigned int*)l,
      16, 0, 0);
}

__device__ __forceinline__ void barrier_raw() {
  asm volatile("" ::: "memory");
  __builtin_amdgcn_s_barrier();
  asm volatile("" ::: "memory");
}
#define VMCNT(n) asm volatile("s_waitcnt vmcnt(" #n ")" ::: "memory")
#define LGKM0 asm volatile("s_waitcnt lgkmcnt(0)" ::: "memory")

// ---------------- f32 -> bf16 convert (vector) ----------------
__global__ __launch_bounds__(256) void cvt_f32_bf16(const float* __restrict__ src,
                                                    bf16* __restrict__ dst, int n4) {
  int i = blockIdx.x * 256 + threadIdx.x;
  if (i >= n4) return;
  const float4 v = ((const float4*)src)[i];
  bf16x4 o = {(bf16)v.x, (bf16)v.y, (bf16)v.z, (bf16)v.w};
  ((bf16x4*)dst)[i] = o;
}

// ---- transpose + convert: dst[C][R] = (bf16)src[R][C], 64(j) x 128(i) dst tiles ----
__global__ __launch_bounds__(512) void transpose_cvt(const float* __restrict__ src,
                                                     bf16* __restrict__ dst, int R, int C) {
  __shared__ float tl[128][68];
  const int j0 = blockIdx.x * 64, i0 = blockIdx.y * 128;
  {
    const int r = threadIdx.x >> 2, c = (threadIdx.x & 3) * 16;
    const float* S = src + (size_t)(i0 + r) * C + j0 + c;
#pragma unroll
    for (int e = 0; e < 4; ++e) *(float4*)&tl[r][c + e * 4] = *(const float4*)&S[e * 4];
  }
  __syncthreads();
  {
    const int j = threadIdx.x >> 3, ic = (threadIdx.x & 7) * 16;
    bf16x8 o0, o1;
#pragma unroll
    for (int e = 0; e < 8; ++e) {
      o0[e] = (bf16)tl[ic + e][j];
      o1[e] = (bf16)tl[ic + 8 + e][j];
    }
    bf16* D = dst + (size_t)(j0 + j) * R + i0 + ic;
    *(bf16x8*)&D[0] = o0;
    *(bf16x8*)&D[8] = o1;
  }
}

// ---------------- bf16 transpose: VT[bk][d][s] = Vtmp[bk][s][d] ----------------
__global__ __launch_bounds__(256) void vtrans(const bf16* __restrict__ src,
                                              bf16* __restrict__ dst) {
  __shared__ bf16 tl[64][72];
  const int bk = blockIdx.z;
  const int s0 = blockIdx.x * 64, d0 = blockIdx.y * 64;
  const bf16* S = src + ((size_t)bk * SEQ + s0) * DH + d0;
  bf16* D = dst + ((size_t)bk * DH + d0) * SEQ + s0;
  const int r = threadIdx.x >> 2, c = (threadIdx.x & 3) * 16;
  *(bf16x8*)&tl[r][c] = *(const bf16x8*)&S[(size_t)r * DH + c];
  *(bf16x8*)&tl[r][c + 8] = *(const bf16x8*)&S[(size_t)r * DH + c + 8];
  __syncthreads();
  bf16x8 o0, o1;
#pragma unroll
  for (int e = 0; e < 8; ++e) {
    o0[e] = tl[c + e][r];
    o1[e] = tl[c + 8 + e][r];
  }
  *(bf16x8*)&D[(size_t)r * SEQ + c] = o0;
  *(bf16x8*)&D[(size_t)r * SEQ + c + 8] = o1;
}

// ======== BK=64 bf16 GEMM, RACE-FREE ledger (certify-before-barrier) ========
// BM=128, BN=256, BK=64, 512 thr (8 waves 2Mx4N), 3 rotating 48KB buffers (144KB).
// R17's ledger had a cross-wave RAW race (reads of tile kt after a barrier that did
// NOT order other waves' in-flight stage(kt) loads).  Fixed pattern (matches the
// proven R8/R15/flash ordering): per tile kt = {stage(kt+2); reads+MFMA(kt);
// VMCNT(6) retires own S(kt+1) [S(kt+2) stays in flight]; LGKM0; barrier}.
// -> every wave certifies its share of tile kt+1 BEFORE the barrier; tile kt+1 is
// read only AFTER it.  WAR on buf((kt+2)%3): last read at kt-1, sealed by that
// iteration's LGKM0+barrier.  Tail: VMCNT(0) at kt=NT-2.
// Swizzle: 128B rows, slot8 ^= row&7, pre-swizzled global source.
// MODE: 0 = f32 C; 2 = fused RoPE epilogue (Q*SCALE / K / V->Vtmp; cos/sin LDS slab).
template <int MODE>
__global__ __launch_bounds__(512, 2) void gemm_dp(const bf16* __restrict__ A,
                                                  const bf16* __restrict__ BT,
                                                  void* __restrict__ Cout,
                                                  int N, int K,
                                                  const float* __restrict__ cosp,
                                                  const float* __restrict__ sinp,
                                                  bf16* __restrict__ Qo,
                                                  bf16* __restrict__ Ko,
                                                  bf16* __restrict__ Vo) {
  extern __shared__ char smem[];
  constexpr int CA = 128 * 64 * 2;  // 16 KiB A chunk
  constexpr int CB = 256 * 64 * 2;  // 32 KiB B chunk
  constexpr int BUF = CA + CB;      // 48 KiB per K-tile buffer
  const int t = threadIdx.x, lane = t & 63, w = t >> 6;
  const int l16 = lane & 15, lq = lane >> 4;
  const int wm = w >> 2, wn = w & 3;

  const int nwg = gridDim.x;  // 384 (gemm1) or 256 (gemm2); both %8==0
  const int lin = ((int)blockIdx.x & 7) * (nwg >> 3) + ((int)blockIdx.x >> 3);
  const int m0 = (lin & 15) * 128;  // m-inner: XCD chunk keeps B panels L2-hot
  const int n0 = (lin >> 4) * 256;

  // staging sources (pre-swizzled global, linear LDS dest); 8KB unit = 64 rows x 128B
  const int srow = t >> 3;
  const int sslot = (t & 7) ^ (srow & 7);
  const bf16* gsrc[6];
  gsrc[0] = A + (size_t)(m0 + srow) * K + sslot * 8;
  gsrc[1] = A + (size_t)(m0 + 64 + srow) * K + sslot * 8;
#pragma unroll
  for (int u = 2; u < 6; ++u)
    gsrc[u] = BT + (size_t)(n0 + (u - 2) * 64 + srow) * K + sslot * 8;

  // swizzled fragment byte offsets for k-half 0; k-half 1 = off ^ 64
  int aoff[4], boff[4];
#pragma unroll
  for (int f = 0; f < 4; ++f) {
    const int ra = wm * 64 + f * 16 + l16;
    aoff[f] = ra * 128 + ((lq ^ (ra & 7)) << 4);
    const int rb = wn * 64 + f * 16 + l16;
    boff[f] = CA + rb * 128 + ((lq ^ (rb & 7)) << 4);
  }

  auto stage = [&](int kt) {
    char* d = smem + (kt % 3) * BUF + t * 16;
#pragma unroll
    for (int u = 0; u < 6; ++u) async16(gsrc[u] + (size_t)kt * 64, d + u * 8192);
  };

  f32x4 acc[4][4] = {};
  const int NT = K >> 6;  // 64

  stage(0);
  stage(1);
  VMCNT(6);  // own S0 retired; S1 in flight
  barrier_raw();  // all waves' S0 landed -> tile 0 readable

  for (int kt = 0; kt < NT; ++kt) {
    const char* buf = smem + (kt % 3) * BUF;
    if (kt + 2 < NT) stage(kt + 2);
#pragma unroll
    for (int kk = 0; kk < 2; ++kk) {
      const int kx = kk * 64;
      bf16x8 af[4], bfr[4];
#pragma unroll
      for (int f = 0; f < 4; ++f) af[f] = *(const bf16x8*)(buf + (aoff[f] ^ kx));
#pragma unroll
      for (int j = 0; j < 4; ++j) bfr[j] = *(const bf16x8*)(buf + (boff[j] ^ kx));
      __builtin_amdgcn_s_setprio(1);
#pragma unroll
      for (int f = 0; f < 4; ++f)
#pragma unroll
        for (int j = 0; j < 4; ++j) acc[f][j] = MFMA(af[f], bfr[j], acc[f][j]);
      __builtin_amdgcn_s_setprio(0);
    }
    if (kt + 2 < NT) {
      VMCNT(6);  // retires own S(kt+1); S(kt+2) stays in flight
    } else if (kt + 1 < NT) {
      VMCNT(0);  // tail: certify S(NT-1)
    }
    LGKM0;          // own ds_reads of buf(kt) complete
    barrier_raw();  // cross-wave: tile kt+1 certified by ALL; buf(kt) reads done
  }

  if constexpr (MODE == 2) {
    // loop-end barrier already sealed all reads; slab overwrite of smem is safe.
    float* csl = (float*)smem;              // [128][64]
    float* snl = (float*)(smem + 32768);    // [128][64]
    const int s0 = m0 & 1023;
    const f32x4* cs = (const f32x4*)(cosp + s0 * 64);
    const f32x4* sn = (const f32x4*)(sinp + s0 * 64);
#pragma unroll
    for (int i = 0; i < 4; ++i) {
      ((f32x4*)csl)[t + i * 512] = cs[t + i * 512];
      ((f32x4*)snl)[t + i * 512] = sn[t + i * 512];
    }
    barrier_raw();
#pragma unroll
    for (int f = 0; f < 4; ++f)
#pragma unroll
      for (int j = 0; j < 4; ++j)
#pragma unroll
        for (int r = 0; r < 4; ++r) {
          const int row = m0 + wm * 64 + f * 16 + lq * 4 + r;
          const int col = n0 + wn * 64 + j * 16 + l16;
          const float v = acc[f][j][r];
          const float part = __shfl_xor(v, 1);
          const int bb = row >> 10, s = row & 1023;
          const int srel = wm * 64 + f * 16 + lq * 4 + r;
          if (col < 4096) {
            const int h = col >> 7, d = col & 127;
            const float c = csl[srel * 64 + (d >> 1)];
            const float sv = snl[srel * 64 + (d >> 1)];
            const float o = (l16 & 1) ? (part * sv + v * c) : (v * c - part * sv);
            Qo[((size_t)(bb * NH + h) * SEQ + s) * DH + d] = (bf16)(o * SCALE);
          } else if (col < 5120) {
            const int idx = col - 4096, kvh = idx >> 7, d = idx & 127;
            const float c = csl[srel * 64 + (d >> 1)];
            const float sv = snl[srel * 64 + (d >> 1)];
            const float o = (l16 & 1) ? (part * sv + v * c) : (v * c - part * sv);
            Ko[((size_t)(bb * NKV + kvh) * SEQ + s) * DH + d] = (bf16)o;
          } else {
            const int idx = col - 5120, kvh = idx >> 7, d = idx & 127;
            Vo[((size_t)(bb * NKV + kvh) * SEQ + s) * DH + d] = (bf16)v;
          }
        }
  } else {
#pragma unroll
    for (int f = 0; f < 4; ++f)
#pragma unroll
      for (int j = 0; j < 4; ++j)
#pragma unroll
        for (int r = 0; r < 4; ++r) {
          const int row = m0 + wm * 64 + f * 16 + lq * 4 + r;
          const int col = n0 + wn * 64 + j * 16 + l16;
          ((float*)Cout)[(size_t)row * N + col] = acc[f][j][r];
        }
  }
}

// ======== causal GQA flash attention v2: 8-wave blocks, LDS-staged K/V (R8/R17) =====
__global__ __launch_bounds__(512, 2) void flash_attn(const bf16* __restrict__ Q,
                                                     const bf16* __restrict__ K,
                                                     const bf16* __restrict__ VT,
                                                     bf16* __restrict__ O) {
  extern __shared__ char smem[];
  const int t = threadIdx.x, lane = t & 63, w = t >> 6;
  const int l16 = lane & 15, lq = lane >> 4;
  const int p = blockIdx.x;
  const int b = p >> 7, h = (p >> 2) & 31, Tb = p & 3;
  const int kvh = h >> 2;

  const bf16* Qb = Q + (size_t)(b * NH + h) * SEQ * DH;
  const bf16* Kb = K + (size_t)(b * NKV + kvh) * SEQ * DH;
  const bf16* Vb = VT + (size_t)(b * NKV + kvh) * DH * SEQ;

  const int qrA = Tb * 128 + w * 16;
  const int qrB = (7 - Tb) * 128 + w * 16;
  const int nAw = (qrA >> 6) + 1;
  const int nBw = (qrB >> 6) + 1;
  const int NT = 16 - 2 * Tb;

  bf16* plw = (bf16*)(smem + 98304) + w * (2 * 16 * 72);

  const bf16* kSrc = Kb + (size_t)(t >> 4) * DH + 8 * ((t & 15) ^ ((t >> 4) & 7));
  const bf16* vSrc = Vb + (size_t)(t >> 3) * SEQ + 8 * ((t & 7) ^ ((t >> 3) & 7));

  auto stage = [&](int kv) {
    char* bufb = smem + (kv % 3) * 32768;
    async16(kSrc + (size_t)(kv * 64) * DH, bufb + t * 16);
    async16(kSrc + (size_t)(kv * 64 + 32) * DH, bufb + 8192 + t * 16);
    async16(vSrc + kv * 64, bufb + 16384 + t * 16);
    async16(vSrc + (size_t)64 * SEQ + kv * 64, bufb + 24576 + t * 16);
  };

  int KX[4], VX[2];
#pragma unroll
  for (int kk = 0; kk < 4; ++kk) KX[kk] = ((kk * 4 + lq) ^ (l16 & 7)) << 4;
#pragma unroll
  for (int c = 0; c < 2; ++c) VX[c] = ((c * 4 + lq) ^ (l16 & 7)) << 4;

  bf16x8 qfA[4], qfB[4];
#pragma unroll
  for (int kk = 0; kk < 4; ++kk) {
    qfA[kk] = *(const bf16x8*)&Qb[(size_t)(qrA + l16) * DH + kk * 32 + lq * 8];
    qfB[kk] = *(const bf16x8*)&Qb[(size_t)(qrB + l16) * DH + kk * 32 + lq * 8];
  }

  f32x4 accA[8] = {}, accB[8] = {};
  float mA[4], lA[4], mB[4], lB[4];
#pragma unroll
  for (int r = 0; r < 4; ++r) {
    mA[r] = mB[r] = -INFINITY;
    lA[r] = lB[r] = 0.f;
  }

  auto finish = [&](f32x4(&s)[4], float(&m)[4], float(&l)[4], f32x4(&acc)[8], int slot,
                    bool mask, int kv, int qr) {
    if (mask) {
#pragma unroll
      for (int nt = 0; nt < 4; ++nt)
#pragma unroll
        for (int r = 0; r < 4; ++r)
          if (kv * 64 + nt * 16 + l16 > qr + lq * 4 + r) s[nt][r] = -INFINITY;
    }
#pragma unroll
    for (int r = 0; r < 4; ++r) {
      float mx = fmaxf(fmaxf(s[0][r], s[1][r]), fmaxf(s[2][r], s[3][r]));
#pragma unroll
      for (int off = 1; off < 16; off <<= 1) mx = fmaxf(mx, __shfl_xor(mx, off));
      const float mn = fmaxf(m[r], mx);
      const float corr = __expf(m[r] - mn);
      m[r] = mn;
      float ps = 0.f;
#pragma unroll
      for (int nt = 0; nt < 4; ++nt) {
        const float pv = __expf(s[nt][r] - mn);
        s[nt][r] = pv;
        ps += pv;
      }
#pragma unroll
      for (int off = 1; off < 16; off <<= 1) ps += __shfl_xor(ps, off);
      l[r] = l[r] * corr + ps;
#pragma unroll
      for (int j = 0; j < 8; ++j) acc[j][r] *= corr;
    }
#pragma unroll
    for (int nt = 0; nt < 4; ++nt)
#pragma unroll
      for (int r = 0; r < 4; ++r)
        plw[slot * 1152 + (lq * 4 + r) * 72 + nt * 16 + l16] = (bf16)s[nt][r];
  };

  stage(0);
  stage(1);
  VMCNT(4);
  barrier_raw();

  for (int kv = 0; kv < NT; ++kv) {
    const char* kbuf = smem + (kv % 3) * 32768;
    const char* vbuf = kbuf + 16384;
    if (kv + 2 < NT) stage(kv + 2);

    if (kv < nAw) {
      f32x4 sA[4] = {}, sB[4] = {};
      __builtin_amdgcn_s_setprio(1);
#pragma unroll
      for (int nt = 0; nt < 4; ++nt) {
        const char* kr = kbuf + (nt * 16 + l16) * 256;
        bf16x8 k0 = *(const bf16x8*)(kr + KX[0]);
        bf16x8 k1 = *(const bf16x8*)(kr + KX[1]);
        bf16x8 k2 = *(const bf16x8*)(kr + KX[2]);
        bf16x8 k3 = *(const bf16x8*)(kr + KX[3]);
        sA[nt] = MFMA(qfA[0], k0, sA[nt]);
        sB[nt] = MFMA(qfB[0], k0, sB[nt]);
        sA[nt] = MFMA(qfA[1], k1, sA[nt]);
        sB[nt] = MFMA(qfB[1], k1, sB[nt]);
        sA[nt] = MFMA(qfA[2], k2, sA[nt]);
        sB[nt] = MFMA(qfB[2], k2, sB[nt]);
        sA[nt] = MFMA(qfA[3], k3, sA[nt]);
        sB[nt] = MFMA(qfB[3], k3, sB[nt]);
      }
      __builtin_amdgcn_s_setprio(0);
      finish(sA, mA, lA, accA, 0, kv == nAw - 1, kv, qrA);
      finish(sB, mB, lB, accB, 1, kv == nBw - 1, kv, qrB);
      bf16x8 pA0 = *(const bf16x8*)&plw[l16 * 72 + lq * 8];
      bf16x8 pA1 = *(const bf16x8*)&plw[l16 * 72 + 32 + lq * 8];
      bf16x8 pB0 = *(const bf16x8*)&plw[1152 + l16 * 72 + lq * 8];
      bf16x8 pB1 = *(const bf16x8*)&plw[1152 + l16 * 72 + 32 + lq * 8];
      __builtin_amdgcn_s_setprio(1);
#pragma unroll
      for (int j = 0; j < 8; ++j) {
        const char* vr = vbuf + (j * 16 + l16) * 128;
        bf16x8 v0 = *(const bf16x8*)(vr + VX[0]);
        bf16x8 v1 = *(const bf16x8*)(vr + VX[1]);
        accA[j] = MFMA(pA0, v0, accA[j]);
        accB[j] = MFMA(pB0, v0, accB[j]);
        accA[j] = MFMA(pA1, v1, accA[j]);
        accB[j] = MFMA(pB1, v1, accB[j]);
      }
      __builtin_amdgcn_s_setprio(0);
    } else if (kv < nBw) {
      f32x4 sB[4] = {};
      __builtin_amdgcn_s_setprio(1);
#pragma unroll
      for (int nt = 0; nt < 4; ++nt) {
        const char* kr = kbuf + (nt * 16 + l16) * 256;
        bf16x8 k0 = *(const bf16x8*)(kr + KX[0]);
        bf16x8 k1 = *(const bf16x8*)(kr + KX[1]);
        bf16x8 k2 = *(const bf16x8*)(kr + KX[2]);
        bf16x8 k3 = *(const bf16x8*)(kr + KX[3]);
        sB[nt] = MFMA(qfB[0], k0, sB[nt]);
        sB[nt] = MFMA(qfB[1], k1, sB[nt]);
        sB[nt] = MFMA(qfB[2], k2, sB[nt]);
        sB[nt] = MFMA(qfB[3], k3, sB[nt]);
      }
      __builtin_amdgcn_s_setprio(0);
      finish(sB, mB, lB, accB, 1, kv == nBw - 1, kv, qrB);
      bf16x8 pB0 = *(const bf16x8*)&plw[1152 + l16 * 72 + lq * 8];
      bf16x8 pB1 = *(const bf16x8*)&plw[1152 + l16 * 72 + 32 + lq * 8];
      __builtin_amdgcn_s_setprio(1);
#pragma unroll
      for (int j = 0; j < 8; ++j) {
        const char* vr = vbuf + (j * 16 + l16) * 128;
        bf16x8 v0 = *(const bf16x8*)(vr + VX[0]);
        bf16x8 v1 = *(const bf16x8*)(vr + VX[1]);
        accB[j] = MFMA(pB0, v0, accB[j]);
        accB[j] = MFMA(pB1, v1, accB[j]);
      }
      __builtin_amdgcn_s_setprio(0);
    }

    if (kv + 2 < NT) { VMCNT(4); } else { VMCNT(0); }
    barrier_raw();
  }

  auto wout = [&](f32x4(&acc)[8], float(&l)[4], int qr) {
#pragma unroll
    for (int r = 0; r < 4; ++r) {
      const float inv = 1.f / l[r];
      const size_t orow = ((size_t)b * SEQ + qr + lq * 4 + r) * HIDN + h * DH;
#pragma unroll
      for (int j = 0; j < 8; ++j) O[orow + j * 16 + l16] = (bf16)(acc[j][r] * inv);
    }
  };
  wout(accA, lA, qrA);
  wout(accB, lB, qrB);
}

extern "C" void kernel_launch(void* const* d_in, const int* in_sizes, int n_in,
                              void* d_out, int out_size, void* d_ws, size_t ws_size,
                              hipStream_t stream) {
  const float* hidden = (const float*)d_in[0];
  const float* cosp = (const float*)d_in[1];
  const float* sinp = (const float*)d_in[2];
  const float* wqkv = (const float*)d_in[3];
  const float* wo = (const float*)d_in[4];
  float* out = (float*)d_out;

  char* ws = (char*)d_ws;
  bf16* hiddenB = (bf16*)(ws);                 // [2048][4096]
  bf16* wqkvT  = (bf16*)(ws + 16777216);       // [6144][4096]
  bf16* woT    = (bf16*)(ws + 67108864);       // [4096][4096]
  bf16* Vtmp   = (bf16*)(ws + 100663296);      // [2][8][1024][128]
  bf16* Qb     = (bf16*)(ws + 125829120);      // [2][32][1024][128]
  bf16* Kb     = (bf16*)(ws + 142606336);      // [2][8][1024][128]
  bf16* VTb    = (bf16*)(ws + 146800640);      // [2][8][128][1024]
  bf16* attnB  = hiddenB;                      // alias: hiddenB dead after gemm1

  cvt_f32_bf16<<<8192, 256, 0, stream>>>(hidden, hiddenB, 2097152);
  transpose_cvt<<<dim3(96, 32), 512, 0, stream>>>(wqkv, wqkvT, 4096, 6144);
  transpose_cvt<<<dim3(64, 32), 512, 0, stream>>>(wo, woT, 4096, 4096);
  gemm_dp<2><<<dim3(384), 512, 147456, stream>>>(hiddenB, wqkvT, nullptr, 6144, 4096,
                                                 cosp, sinp, Qb, Kb, Vtmp);
  vtrans<<<dim3(16, 2, 16), 256, 0, stream>>>(Vtmp, VTb);
  flash_attn<<<dim3(256), 512, 135168, stream>>>(Qb, Kb, VTb, attnB);
  gemm_dp<0><<<dim3(256), 512, 147456, stream>>>(attnB, woT, out, 4096, 4096,
                                                 nullptr, nullptr, nullptr, nullptr,
                                                 nullptr);
}

// Round 21
// 282.140 us; speedup vs baseline: 1.1231x; 1.1231x over previous
//
#include <hip/hip_runtime.h>
#include <hip/hip_bf16.h>

typedef __bf16 bf16;
typedef __attribute__((ext_vector_type(2))) __bf16 bf16x2;
typedef __attribute__((ext_vector_type(4))) __bf16 bf16x4;
typedef __attribute__((ext_vector_type(8))) __bf16 bf16x8;
typedef __attribute__((ext_vector_type(4))) float f32x4;

#define NB 2
#define SEQ 1024
#define HIDN 4096
#define NH 32
#define NKV 8
#define DH 128
#define QKV_N 6144
static constexpr float SCALE = 0.08838834764831845f;  // 1/sqrt(128)

#define MFMA(a, b, c) __builtin_amdgcn_mfma_f32_16x16x32_bf16((a), (b), (c), 0, 0, 0)

__device__ __forceinline__ void async16(const void* g, void* l) {
  __builtin_amdgcn_global_load_lds(
      (const __attribute__((address_space(1))) unsigned int*)g,
      (__attribute__((address_space(3))) unsigned int*)l,
      16, 0, 0);
}

__device__ __forceinline__ void barrier_raw() {
  asm volatile("" ::: "memory");
  __builtin_amdgcn_s_barrier();
  asm volatile("" ::: "memory");
}
#define VMCNT(n) asm volatile("s_waitcnt vmcnt(" #n ")" ::: "memory")
#define LGKM0 asm volatile("s_waitcnt lgkmcnt(0)" ::: "memory")

// ---------------- f32 -> bf16 convert (vector) ----------------
__global__ __launch_bounds__(256) void cvt_f32_bf16(const float* __restrict__ src,
                                                    bf16* __restrict__ dst, int n4) {
  int i = blockIdx.x * 256 + threadIdx.x;
  if (i >= n4) return;
  const float4 v = ((const float4*)src)[i];
  bf16x4 o = {(bf16)v.x, (bf16)v.y, (bf16)v.z, (bf16)v.w};
  ((bf16x4*)dst)[i] = o;
}

// ---- transpose + convert (R20-validated): 64(j) x 128(i) dst tiles, 512 thr ----
__global__ __launch_bounds__(512) void transpose_cvt(const float* __restrict__ src,
                                                     bf16* __restrict__ dst, int R, int C) {
  __shared__ float tl[128][68];
  const int j0 = blockIdx.x * 64, i0 = blockIdx.y * 128;
  {
    const int r = threadIdx.x >> 2, c = (threadIdx.x & 3) * 16;
    const float* S = src + (size_t)(i0 + r) * C + j0 + c;
#pragma unroll
    for (int e = 0; e < 4; ++e) *(float4*)&tl[r][c + e * 4] = *(const float4*)&S[e * 4];
  }
  __syncthreads();
  {
    const int j = threadIdx.x >> 3, ic = (threadIdx.x & 7) * 16;
    bf16x8 o0, o1;
#pragma unroll
    for (int e = 0; e < 8; ++e) {
      o0[e] = (bf16)tl[ic + e][j];
      o1[e] = (bf16)tl[ic + 8 + e][j];
    }
    bf16* D = dst + (size_t)(j0 + j) * R + i0 + ic;
    *(bf16x8*)&D[0] = o0;
    *(bf16x8*)&D[8] = o1;
  }
}

// ---------------- bf16 transpose: VT[bk][d][s] = Vtmp[bk][s][d] ----------------
__global__ __launch_bounds__(256) void vtrans(const bf16* __restrict__ src,
                                              bf16* __restrict__ dst) {
  __shared__ bf16 tl[64][72];
  const int bk = blockIdx.z;
  const int s0 = blockIdx.x * 64, d0 = blockIdx.y * 64;
  const bf16* S = src + ((size_t)bk * SEQ + s0) * DH + d0;
  bf16* D = dst + ((size_t)bk * DH + d0) * SEQ + s0;
  const int r = threadIdx.x >> 2, c = (threadIdx.x & 3) * 16;
  *(bf16x8*)&tl[r][c] = *(const bf16x8*)&S[(size_t)r * DH + c];
  *(bf16x8*)&tl[r][c + 8] = *(const bf16x8*)&S[(size_t)r * DH + c + 8];
  __syncthreads();
  bf16x8 o0, o1;
#pragma unroll
  for (int e = 0; e < 8; ++e) {
    o0[e] = tl[c + e][r];
    o1[e] = tl[c + 8 + e][r];
  }
  *(bf16x8*)&D[(size_t)r * SEQ + c] = o0;
  *(bf16x8*)&D[(size_t)r * SEQ + c + 8] = o1;
}

// ======== R15 GEMM (BK=32, 4 buffers, certify-before-barrier; validated 282.7us run)
// + LGKM0 before the 2nd in-loop barrier (seals the WAR window: stage(kt+3) may not
// overwrite buf(kt-1) until every wave's ds_reads of it completed).
// MODE: 0 = f32 C; 2 = fused RoPE epilogue (Q*SCALE / K / V->Vtmp; cos/sin LDS slab).
template <int BN, int MODE>
__global__ __launch_bounds__(512, 2) void gemm_dp(const bf16* __restrict__ A,
                                                  const bf16* __restrict__ BT,
                                                  void* __restrict__ Cout,
                                                  int N, int K,
                                                  const float* __restrict__ cosp,
                                                  const float* __restrict__ sinp,
                                                  bf16* __restrict__ Qo,
                                                  bf16* __restrict__ Ko,
                                                  bf16* __restrict__ Vo) {
  extern __shared__ char smem[];
  constexpr int CA = 128 * 32 * 2;
  constexpr int CB = BN * 32 * 2;
  constexpr int BUF = CA + CB;
  constexpr int LTOT = 1 + BN / 128;
  constexpr int FN = BN / 64;
  constexpr int FNH = FN / 2;
  const int t = threadIdx.x, lane = t & 63, w = t >> 6;
  const int l16 = lane & 15, lq = lane >> 4;
  const int wm = w >> 2, wn = w & 3;

  const int nwg = gridDim.x;  // 256
  const int lin = ((int)blockIdx.x & 7) * (nwg >> 3) + ((int)blockIdx.x >> 3);
  const int m0 = (lin & 15) * 128;
  const int n0 = (lin >> 4) * BN;

  const int sslot = (t & 3) ^ ((t >> 3) & 3);
  const bf16* gsrc[LTOT];
  gsrc[0] = A + (size_t)(m0 + (t >> 2)) * K + sslot * 8;
#pragma unroll
  for (int u = 1; u < LTOT; ++u)
    gsrc[u] = BT + (size_t)(n0 + (u - 1) * 128 + (t >> 2)) * K + sslot * 8;

  int abyte[4], bbyte[FN];
#pragma unroll
  for (int f = 0; f < 4; ++f) {
    const int r = wm * 64 + f * 16 + l16;
    abyte[f] = r * 64 + ((lq ^ ((r >> 1) & 3)) << 4);
  }
#pragma unroll
  for (int j = 0; j < FN; ++j) {
    const int r = wn * (BN / 4) + j * 16 + l16;
    bbyte[j] = CA + r * 64 + ((lq ^ ((r >> 1) & 3)) << 4);
  }

  auto stage_unit = [&](int kt, int u) {
    char* d = smem + (kt & 3) * BUF + u * 8192 + t * 16;
    async16(gsrc[u] + (size_t)kt * 32, d);
  };

  f32x4 acc[4][FN] = {};
  const int NT = K >> 5;  // 128

#pragma unroll
  for (int kt = 0; kt < 3; ++kt)
#pragma unroll
    for (int u = 0; u < LTOT; ++u) stage_unit(kt, u);
  if constexpr (LTOT == 4) { VMCNT(8); } else { VMCNT(6); }
  barrier_raw();

  for (int kt = 0; kt < NT; ++kt) {
    const char* buf = smem + (kt & 3) * BUF;
    const bool pf = (kt + 3 < NT);
    bf16x8 af[4], bf0[FNH];
#pragma unroll
    for (int f = 0; f < 4; ++f) af[f] = *(const bf16x8*)(buf + abyte[f]);
#pragma unroll
    for (int j = 0; j < FNH; ++j) bf0[j] = *(const bf16x8*)(buf + bbyte[j]);
    if (pf) {
      stage_unit(kt + 3, 0);
      stage_unit(kt + 3, 1);
    }
    barrier_raw();
    __builtin_amdgcn_s_setprio(1);
#pragma unroll
    for (int f = 0; f < 4; ++f)
#pragma unroll
      for (int j = 0; j < FNH; ++j) acc[f][j] = MFMA(af[f], bf0[j], acc[f][j]);
    __builtin_amdgcn_s_setprio(0);
    bf16x8 bf1[FN - FNH];
#pragma unroll
    for (int j = 0; j < FN - FNH; ++j) bf1[j] = *(const bf16x8*)(buf + bbyte[FNH + j]);
    if (pf) {
#pragma unroll
      for (int u = 2; u < LTOT; ++u) stage_unit(kt + 3, u);
    }
    if (pf) {
      if constexpr (LTOT == 4) { VMCNT(8); } else { VMCNT(6); }
    } else if (kt + 2 < NT) {
      if constexpr (LTOT == 4) { VMCNT(4); } else { VMCNT(3); }
    } else {
      VMCNT(0);
    }
    LGKM0;  // all this wave's ds_reads of buf(kt) done -> WAR for stage(kt+4) sealed
    barrier_raw();
    __builtin_amdgcn_s_setprio(1);
#pragma unroll
    for (int f = 0; f < 4; ++f)
#pragma unroll
      for (int j = 0; j < FN - FNH; ++j)
        acc[f][FNH + j] = MFMA(af[f], bf1[j], acc[f][FNH + j]);
    __builtin_amdgcn_s_setprio(0);
  }

  if constexpr (MODE == 2) {
    LGKM0;
    barrier_raw();
    float* csl = (float*)smem;              // [128][64]
    float* snl = (float*)(smem + 32768);    // [128][64]
    const int s0 = m0 & 1023;
    const f32x4* cs = (const f32x4*)(cosp + s0 * 64);
    const f32x4* sn = (const f32x4*)(sinp + s0 * 64);
#pragma unroll
    for (int i = 0; i < 4; ++i) {
      ((f32x4*)csl)[t + i * 512] = cs[t + i * 512];
      ((f32x4*)snl)[t + i * 512] = sn[t + i * 512];
    }
    barrier_raw();
#pragma unroll
    for (int f = 0; f < 4; ++f)
#pragma unroll
      for (int j = 0; j < FN; ++j)
#pragma unroll
        for (int r = 0; r < 4; ++r) {
          const int row = m0 + wm * 64 + f * 16 + lq * 4 + r;
          const int col = n0 + wn * (BN / 4) + j * 16 + l16;
          const float v = acc[f][j][r];
          const float part = __shfl_xor(v, 1);
          const int bb = row >> 10, s = row & 1023;
          const int srel = wm * 64 + f * 16 + lq * 4 + r;
          if (col < 4096) {
            const int h = col >> 7, d = col & 127;
            const float c = csl[srel * 64 + (d >> 1)];
            const float sv = snl[srel * 64 + (d >> 1)];
            const float o = (l16 & 1) ? (part * sv + v * c) : (v * c - part * sv);
            Qo[((size_t)(bb * NH + h) * SEQ + s) * DH + d] = (bf16)(o * SCALE);
          } else if (col < 5120) {
            const int idx = col - 4096, kvh = idx >> 7, d = idx & 127;
            const float c = csl[srel * 64 + (d >> 1)];
            const float sv = snl[srel * 64 + (d >> 1)];
            const float o = (l16 & 1) ? (part * sv + v * c) : (v * c - part * sv);
            Ko[((size_t)(bb * NKV + kvh) * SEQ + s) * DH + d] = (bf16)o;
          } else {
            const int idx = col - 5120, kvh = idx >> 7, d = idx & 127;
            Vo[((size_t)(bb * NKV + kvh) * SEQ + s) * DH + d] = (bf16)v;
          }
        }
  } else {
#pragma unroll
    for (int f = 0; f < 4; ++f)
#pragma unroll
      for (int j = 0; j < FN; ++j)
#pragma unroll
        for (int r = 0; r < 4; ++r) {
          const int row = m0 + wm * 64 + f * 16 + lq * 4 + r;
          const int col = n0 + wn * (BN / 4) + j * 16 + l16;
          ((float*)Cout)[(size_t)row * N + col] = acc[f][j][r];
        }
  }
}

// ======== causal GQA flash attention v2: 8-wave blocks, LDS-staged K/V (validated) ==
__global__ __launch_bounds__(512, 2) void flash_attn(const bf16* __restrict__ Q,
                                                     const bf16* __restrict__ K,
                                                     const bf16* __restrict__ VT,
                                                     bf16* __restrict__ O) {
  extern __shared__ char smem[];
  const int t = threadIdx.x, lane = t & 63, w = t >> 6;
  const int l16 = lane & 15, lq = lane >> 4;
  const int p = blockIdx.x;
  const int b = p >> 7, h = (p >> 2) & 31, Tb = p & 3;
  const int kvh = h >> 2;

  const bf16* Qb = Q + (size_t)(b * NH + h) * SEQ * DH;
  const bf16* Kb = K + (size_t)(b * NKV + kvh) * SEQ * DH;
  const bf16* Vb = VT + (size_t)(b * NKV + kvh) * DH * SEQ;

  const int qrA = Tb * 128 + w * 16;
  const int qrB = (7 - Tb) * 128 + w * 16;
  const int nAw = (qrA >> 6) + 1;
  const int nBw = (qrB >> 6) + 1;
  const int NT = 16 - 2 * Tb;

  bf16* plw = (bf16*)(smem + 98304) + w * (2 * 16 * 72);

  const bf16* kSrc = Kb + (size_t)(t >> 4) * DH + 8 * ((t & 15) ^ ((t >> 4) & 7));
  const bf16* vSrc = Vb + (size_t)(t >> 3) * SEQ + 8 * ((t & 7) ^ ((t >> 3) & 7));

  auto stage = [&](int kv) {
    char* bufb = smem + (kv % 3) * 32768;
    async16(kSrc + (size_t)(kv * 64) * DH, bufb + t * 16);
    async16(kSrc + (size_t)(kv * 64 + 32) * DH, bufb + 8192 + t * 16);
    async16(vSrc + kv * 64, bufb + 16384 + t * 16);
    async16(vSrc + (size_t)64 * SEQ + kv * 64, bufb + 24576 + t * 16);
  };

  int KX[4], VX[2];
#pragma unroll
  for (int kk = 0; kk < 4; ++kk) KX[kk] = ((kk * 4 + lq) ^ (l16 & 7)) << 4;
#pragma unroll
  for (int c = 0; c < 2; ++c) VX[c] = ((c * 4 + lq) ^ (l16 & 7)) << 4;

  bf16x8 qfA[4], qfB[4];
#pragma unroll
  for (int kk = 0; kk < 4; ++kk) {
    qfA[kk] = *(const bf16x8*)&Qb[(size_t)(qrA + l16) * DH + kk * 32 + lq * 8];
    qfB[kk] = *(const bf16x8*)&Qb[(size_t)(qrB + l16) * DH + kk * 32 + lq * 8];
  }

  f32x4 accA[8] = {}, accB[8] = {};
  float mA[4], lA[4], mB[4], lB[4];
#pragma unroll
  for (int r = 0; r < 4; ++r) {
    mA[r] = mB[r] = -INFINITY;
    lA[r] = lB[r] = 0.f;
  }

  auto finish = [&](f32x4(&s)[4], float(&m)[4], float(&l)[4], f32x4(&acc)[8], int slot,
                    bool mask, int kv, int qr) {
    if (mask) {
#pragma unroll
      for (int nt = 0; nt < 4; ++nt)
#pragma unroll
        for (int r = 0; r < 4; ++r)
          if (kv * 64 + nt * 16 + l16 > qr + lq * 4 + r) s[nt][r] = -INFINITY;
    }
#pragma unroll
    for (int r = 0; r < 4; ++r) {
      float mx = fmaxf(fmaxf(s[0][r], s[1][r]), fmaxf(s[2][r], s[3][r]));
#pragma unroll
      for (int off = 1; off < 16; off <<= 1) mx = fmaxf(mx, __shfl_xor(mx, off));
      const float mn = fmaxf(m[r], mx);
      const float corr = __expf(m[r] - mn);
      m[r] = mn;
      float ps = 0.f;
#pragma unroll
      for (int nt = 0; nt < 4; ++nt) {
        const float pv = __expf(s[nt][r] - mn);
        s[nt][r] = pv;
        ps += pv;
      }
#pragma unroll
      for (int off = 1; off < 16; off <<= 1) ps += __shfl_xor(ps, off);
      l[r] = l[r] * corr + ps;
#pragma unroll
      for (int j = 0; j < 8; ++j) acc[j][r] *= corr;
    }
#pragma unroll
    for (int nt = 0; nt < 4; ++nt)
#pragma unroll
      for (int r = 0; r < 4; ++r)
        plw[slot * 1152 + (lq * 4 + r) * 72 + nt * 16 + l16] = (bf16)s[nt][r];
  };

  stage(0);
  stage(1);
  VMCNT(4);
  barrier_raw();

  for (int kv = 0; kv < NT; ++kv) {
    const char* kbuf = smem + (kv % 3) * 32768;
    const char* vbuf = kbuf + 16384;
    if (kv + 2 < NT) stage(kv + 2);

    if (kv < nAw) {
      f32x4 sA[4] = {}, sB[4] = {};
      __builtin_amdgcn_s_setprio(1);
#pragma unroll
      for (int nt = 0; nt < 4; ++nt) {
        const char* kr = kbuf + (nt * 16 + l16) * 256;
        bf16x8 k0 = *(const bf16x8*)(kr + KX[0]);
        bf16x8 k1 = *(const bf16x8*)(kr + KX[1]);
        bf16x8 k2 = *(const bf16x8*)(kr + KX[2]);
        bf16x8 k3 = *(const bf16x8*)(kr + KX[3]);
        sA[nt] = MFMA(qfA[0], k0, sA[nt]);
        sB[nt] = MFMA(qfB[0], k0, sB[nt]);
        sA[nt] = MFMA(qfA[1], k1, sA[nt]);
        sB[nt] = MFMA(qfB[1], k1, sB[nt]);
        sA[nt] = MFMA(qfA[2], k2, sA[nt]);
        sB[nt] = MFMA(qfB[2], k2, sB[nt]);
        sA[nt] = MFMA(qfA[3], k3, sA[nt]);
        sB[nt] = MFMA(qfB[3], k3, sB[nt]);
      }
      __builtin_amdgcn_s_setprio(0);
      finish(sA, mA, lA, accA, 0, kv == nAw - 1, kv, qrA);
      finish(sB, mB, lB, accB, 1, kv == nBw - 1, kv, qrB);
      bf16x8 pA0 = *(const bf16x8*)&plw[l16 * 72 + lq * 8];
      bf16x8 pA1 = *(const bf16x8*)&plw[l16 * 72 + 32 + lq * 8];
      bf16x8 pB0 = *(const bf16x8*)&plw[1152 + l16 * 72 + lq * 8];
      bf16x8 pB1 = *(const bf16x8*)&plw[1152 + l16 * 72 + 32 + lq * 8];
      __builtin_amdgcn_s_setprio(1);
#pragma unroll
      for (int j = 0; j < 8; ++j) {
        const char* vr = vbuf + (j * 16 + l16) * 128;
        bf16x8 v0 = *(const bf16x8*)(vr + VX[0]);
        bf16x8 v1 = *(const bf16x8*)(vr + VX[1]);
        accA[j] = MFMA(pA0, v0, accA[j]);
        accB[j] = MFMA(pB0, v0, accB[j]);
        accA[j] = MFMA(pA1, v1, accA[j]);
        accB[j] = MFMA(pB1, v1, accB[j]);
      }
      __builtin_amdgcn_s_setprio(0);
    } else if (kv < nBw) {
      f32x4 sB[4] = {};
      __builtin_amdgcn_s_setprio(1);
#pragma unroll
      for (int nt = 0; nt < 4; ++nt) {
        const char* kr = kbuf + (nt * 16 + l16) * 256;
        bf16x8 k0 = *(const bf16x8*)(kr + KX[0]);
        bf16x8 k1 = *(const bf16x8*)(kr + KX[1]);
        bf16x8 k2 = *(const bf16x8*)(kr + KX[2]);
        bf16x8 k3 = *(const bf16x8*)(kr + KX[3]);
        sB[nt] = MFMA(qfB[0], k0, sB[nt]);
        sB[nt] = MFMA(qfB[1], k1, sB[nt]);
        sB[nt] = MFMA(qfB[2], k2, sB[nt]);
        sB[nt] = MFMA(qfB[3], k3, sB[nt]);
      }
      __builtin_amdgcn_s_setprio(0);
      finish(sB, mB, lB, accB, 1, kv == nBw - 1, kv, qrB);
      bf16x8 pB0 = *(const bf16x8*)&plw[1152 + l16 * 72 + lq * 8];
      bf16x8 pB1 = *(const bf16x8*)&plw[1152 + l16 * 72 + 32 + lq * 8];
      __builtin_amdgcn_s_setprio(1);
#pragma unroll
      for (int j = 0; j < 8; ++j) {
        const char* vr = vbuf + (j * 16 + l16) * 128;
        bf16x8 v0 = *(const bf16x8*)(vr + VX[0]);
        bf16x8 v1 = *(const bf16x8*)(vr + VX[1]);
        accB[j] = MFMA(pB0, v0, accB[j]);
        accB[j] = MFMA(pB1, v1, accB[j]);
      }
      __builtin_amdgcn_s_setprio(0);
    }

    if (kv + 2 < NT) { VMCNT(4); } else { VMCNT(0); }
    barrier_raw();
  }

  auto wout = [&](f32x4(&acc)[8], float(&l)[4], int qr) {
#pragma unroll
    for (int r = 0; r < 4; ++r) {
      const float inv = 1.f / l[r];
      const size_t orow = ((size_t)b * SEQ + qr + lq * 4 + r) * HIDN + h * DH;
#pragma unroll
      for (int j = 0; j < 8; ++j) O[orow + j * 16 + l16] = (bf16)(acc[j][r] * inv);
    }
  };
  wout(accA, lA, qrA);
  wout(accB, lB, qrB);
}

extern "C" void kernel_launch(void* const* d_in, const int* in_sizes, int n_in,
                              void* d_out, int out_size, void* d_ws, size_t ws_size,
                              hipStream_t stream) {
  const float* hidden = (const float*)d_in[0];
  const float* cosp = (const float*)d_in[1];
  const float* sinp = (const float*)d_in[2];
  const float* wqkv = (const float*)d_in[3];
  const float* wo = (const float*)d_in[4];
  float* out = (float*)d_out;

  char* ws = (char*)d_ws;
  bf16* hiddenB = (bf16*)(ws);                 // [2048][4096]
  bf16* wqkvT  = (bf16*)(ws + 16777216);       // [6144][4096]
  bf16* woT    = (bf16*)(ws + 67108864);       // [4096][4096]
  bf16* Vtmp   = (bf16*)(ws + 100663296);      // [2][8][1024][128]
  bf16* Qb     = (bf16*)(ws + 125829120);      // [2][32][1024][128]
  bf16* Kb     = (bf16*)(ws + 142606336);      // [2][8][1024][128]
  bf16* VTb    = (bf16*)(ws + 146800640);      // [2][8][128][1024]
  bf16* attnB  = hiddenB;                      // alias: hiddenB dead after gemm1

  cvt_f32_bf16<<<8192, 256, 0, stream>>>(hidden, hiddenB, 2097152);
  transpose_cvt<<<dim3(96, 32), 512, 0, stream>>>(wqkv, wqkvT, 4096, 6144);
  transpose_cvt<<<dim3(64, 32), 512, 0, stream>>>(wo, woT, 4096, 4096);
  gemm_dp<384, 2><<<dim3(256), 512, 131072, stream>>>(hiddenB, wqkvT, nullptr, 6144, 4096,
                                                      cosp, sinp, Qb, Kb, Vtmp);
  vtrans<<<dim3(16, 2, 16), 256, 0, stream>>>(Vtmp, VTb);
  flash_attn<<<dim3(256), 512, 135168, stream>>>(Qb, Kb, VTb, attnB);
  gemm_dp<256, 0><<<dim3(256), 512, 98304, stream>>>(attnB, woT, out, 4096, 4096,
                                                     nullptr, nullptr, nullptr, nullptr,
                                                     nullptr);
}